// Round 1
// baseline (337.600 us; speedup 1.0000x reference)
//
#include <hip/hip_runtime.h>

// Sinkhorn, B=8 N=1024 C=64, T=2, eps=0.1, 20 iters, scale=1e-3.
// Only batch 7 contributes (reference returns losses[-1]).
// Row/col normalization scan == diagonal scaling: P = diag(u) K diag(v),
// u = 1/(K v), v = 1/(K^T u), 20 rounds; loss = sum u_i K_ij v_j W_ij,
// W_ij = -0.1*log(K_ij).
//
// THIS VERSION: single persistent kernel. 44 dispatches -> 1 kernel + 1 memset.
//  - grid = 256 blocks (== #CUs) x 256 threads; co-residency guaranteed
//    (<=21KB LDS, <128 VGPR -> >=2 blocks/CU capacity, grid fits w/ huge margin).
//  - grid barriers: monotonic counter in ws, agent-scope relaxed atomics (LLC).
//    Loop barriers carry NO cache fences: u/v are accessed ONLY via agent-scope
//    atomics (performed at the coherent LLC, bypassing non-coherent XCD L2s),
//    and K/KT rows live in VGPRs, so there is nothing stale to invalidate.
//  - The two phase transitions that publish normal stores (softmax->buildK,
//    buildK->row preload) use release/acquire fenced barriers.
//  - Numerics are bitwise-identical to the previous passing kernel (same dot
//    partitioning j = lane + 64k, same expressions, same loss read order).

static constexpr int N = 1024;
static constexpr int C = 64;
static constexpr unsigned NBLK = 256;

// Workspace layout (floats).
static constexpr int WS_XS  = 0;          // softmax(y_s[7]/2) : 1024*64
static constexpr int WS_YS  = 65536;      // softmax(y_t[7]/2) : 1024*64
static constexpr int WS_K   = 131072;     // K   : 1024*1024
static constexpr int WS_KT  = 1179648;    // K^T : 1024*1024
static constexpr int WS_U   = 2228224;    // u : 1024
static constexpr int WS_V   = 2229248;    // v : 1024
static constexpr int WS_P   = 2230272;    // block partials : 256
static constexpr int WS_BAR = 2230592;    // grid-barrier counter (own line)

__device__ __forceinline__ float wsum(float v) {
    #pragma unroll
    for (int o = 32; o > 0; o >>= 1) v += __shfl_down(v, o, 64);
    return v;
}
__device__ __forceinline__ float wmax(float v) {
    #pragma unroll
    for (int o = 32; o > 0; o >>= 1) v = fmaxf(v, __shfl_down(v, o, 64));
    return v;
}

__device__ __forceinline__ float aload(float* p) {
    return __hip_atomic_load(p, __ATOMIC_RELAXED, __HIP_MEMORY_SCOPE_AGENT);
}
__device__ __forceinline__ void astore(float* p, float v) {
    __hip_atomic_store(p, v, __ATOMIC_RELAXED, __HIP_MEMORY_SCOPE_AGENT);
}

// Monotonic-counter grid barrier. Every block calls this the same number of
// times; `bar` is each thread's local call count. No counter reset -> no
// reset/reuse race. thread0 arrives (after __syncthreads drained this block's
// vmcnt, so all its agent-scope u/v stores are at the LLC) and spins until all
// NBLK arrivals for this generation are in.
template <bool FENCE>
__device__ __forceinline__ void gridbar(unsigned* cnt, unsigned& bar) {
    __syncthreads();
    ++bar;
    if (threadIdx.x == 0) {
        if (FENCE) __builtin_amdgcn_fence(__ATOMIC_RELEASE, "agent");
        __hip_atomic_fetch_add(cnt, 1u, __ATOMIC_RELAXED, __HIP_MEMORY_SCOPE_AGENT);
        while (__hip_atomic_load(cnt, __ATOMIC_RELAXED, __HIP_MEMORY_SCOPE_AGENT)
               < bar * NBLK)
            __builtin_amdgcn_s_sleep(2);
        if (FENCE) __builtin_amdgcn_fence(__ATOMIC_ACQUIRE, "agent");
    }
    asm volatile("" ::: "memory");   // compiler fence: nothing moves across
    __syncthreads();
}

__global__ void __launch_bounds__(256)
sinkhorn_fused(const float* __restrict__ ysrc, const float* __restrict__ ytrc,
               float* __restrict__ ws, float* __restrict__ out)
{
    __shared__ alignas(16) float smem[5184];  // buildK: sx 2048 | sy 2080 | kt 1056
    const int tid = threadIdx.x, bid = blockIdx.x;
    const int wid = tid >> 6, lane = tid & 63;
    unsigned bar = 0;
    unsigned* cnt = (unsigned*)(ws + WS_BAR);

    // ---- Phase A: softmax over N axis (dim=1), batch 7. Blocks 0..127.
    if (bid < 2 * C) {
        float* sm = smem + 5120;
        const float* src = ((bid < C) ? ysrc : ytrc) + 7 * N * C;
        float* dst = ws + ((bid < C) ? WS_XS : WS_YS);
        const int c = bid & (C - 1);
        float vals[4];
        float m = -1e30f;
        #pragma unroll
        for (int q = 0; q < 4; ++q) {
            vals[q] = src[(q * 256 + tid) * C + c] * 0.5f;   // y / T, T = 2
            m = fmaxf(m, vals[q]);
        }
        m = wmax(m);
        if (lane == 0) sm[wid] = m;
        __syncthreads();
        m = fmaxf(fmaxf(sm[0], sm[1]), fmaxf(sm[2], sm[3]));
        float s = 0.f;
        #pragma unroll
        for (int q = 0; q < 4; ++q) { vals[q] = expf(vals[q] - m); s += vals[q]; }
        s = wsum(s);
        __syncthreads();
        if (lane == 0) sm[wid] = s;
        __syncthreads();
        s = sm[0] + sm[1] + sm[2] + sm[3];
        const float inv = 1.0f / s;
        #pragma unroll
        for (int q = 0; q < 4; ++q) dst[(q * 256 + tid) * C + c] = vals[q] * inv;
    }
    gridbar<true>(cnt, bar);     // publish XS/YS (normal stores)

    // ---- Phase B: K_ij = exp(-10 * sum_c |x_ic - y_jc|), plus K^T. v := 1.
    {
        float* xs  = ws + WS_XS;
        float* ysm = ws + WS_YS;
        float* K   = ws + WS_K;
        float* KT  = ws + WS_KT;
        if (bid < 4) astore(ws + WS_V + bid * 256 + tid, 1.0f);  // LLC-direct

        float* sx = smem;
        float* sy = smem + 2048;
        float* kt = smem + 4128;
        #pragma unroll 1
        for (int t = 0; t < 4; ++t) {
            const int tt = bid * 4 + t;
            const int ti = tt >> 5, tj = tt & 31;
            __syncthreads();
            for (int k = tid; k < 2048; k += 256) sx[k] = xs[ti * 2048 + k];
            for (int k = tid; k < 2048; k += 256)
                sy[(k >> 6) * 65 + (k & 63)] = ysm[tj * 2048 + k];
            __syncthreads();
            float kv[4];
            #pragma unroll
            for (int q = 0; q < 4; ++q) {
                const int idx = q * 256 + tid;
                const int il = idx >> 5, jl = idx & 31;
                float a = 0.f;
                #pragma unroll
                for (int c2 = 0; c2 < 64; ++c2)
                    a += fabsf(sx[il * 64 + c2] - sy[jl * 65 + c2]);
                kv[q] = expf(-10.0f * a);                       // exp(-W/eps)
                K[(ti * 32 + il) * N + tj * 32 + jl] = kv[q];
            }
            __syncthreads();
            #pragma unroll
            for (int q = 0; q < 4; ++q) {
                const int idx = q * 256 + tid;
                kt[(idx >> 5) * 33 + (idx & 31)] = kv[q];
            }
            __syncthreads();
            #pragma unroll
            for (int q = 0; q < 4; ++q) {
                const int idx = q * 256 + tid;
                const int jl = idx >> 5, il = idx & 31;
                KT[(tj * 32 + jl) * N + ti * 32 + il] = kt[il * 33 + jl];
            }
        }
    }
    gridbar<true>(cnt, bar);     // publish K/KT (normal stores)

    // ---- Phase C: per-wave register preload of K row r and KT row r.
    // Row = 1024 floats = 64 lanes x 4 float4 -> 16 VGPR per matrix per lane.
    const int r = bid * 4 + wid;
    float4 Ka[4], Kb[4];
    {
        const float4* Kr4  = (const float4*)(ws + WS_K  + r * N);
        const float4* KTr4 = (const float4*)(ws + WS_KT + r * N);
        #pragma unroll
        for (int k = 0; k < 4; ++k) {
            Ka[k] = Kr4[lane + 64 * k];
            Kb[k] = KTr4[lane + 64 * k];
        }
    }

    float* sv  = smem;                 // 1024-float vector staging
    float* wsU = ws + WS_U;
    float* wsV = ws + WS_V;
    float  u_r = 0.f;

    // ---- Phase D: 20 x { u = 1/(K v) ; v = 1/(K^T u) }, fence-free barriers.
    #pragma unroll 1
    for (int it = 0; it < 20; ++it) {
        // stage v (LLC -> LDS), dot with in-register K row
        #pragma unroll
        for (int q = 0; q < 4; ++q) sv[q * 256 + tid] = aload(wsV + q * 256 + tid);
        __syncthreads();
        float acc = 0.f;
        #pragma unroll
        for (int k = 0; k < 4; ++k) {
            const float4 kk = Ka[k];
            const float4 vv = *(const float4*)&sv[(lane + 64 * k) * 4];
            acc += kk.x * vv.x + kk.y * vv.y + kk.z * vv.z + kk.w * vv.w;
        }
        acc = wsum(acc);
        if (lane == 0) { u_r = 1.0f / acc; astore(wsU + r, u_r); }
        gridbar<false>(cnt, bar);

        // stage u, dot with in-register KT row
        #pragma unroll
        for (int q = 0; q < 4; ++q) sv[q * 256 + tid] = aload(wsU + q * 256 + tid);
        __syncthreads();
        acc = 0.f;
        #pragma unroll
        for (int k = 0; k < 4; ++k) {
            const float4 kk = Kb[k];
            const float4 uu = *(const float4*)&sv[(lane + 64 * k) * 4];
            acc += kk.x * uu.x + kk.y * uu.y + kk.z * uu.z + kk.w * uu.w;
        }
        acc = wsum(acc);
        if (lane == 0) astore(wsV + r, 1.0f / acc);
        gridbar<false>(cnt, bar);
    }

    // ---- Phase E: loss partials, bitwise-matching the old loss_partial_k
    // (K re-read from global in the same scalar order; v values via LLC).
    #pragma unroll
    for (int q = 0; q < 4; ++q) sv[q * 256 + tid] = aload(wsV + q * 256 + tid);
    __syncthreads();
    {
        const float* K = ws + WS_K;
        float acc = 0.f;
        for (int j = lane; j < N; j += 64) {
            const float kk = K[r * N + j];
            acc += kk * sv[j] * logf(kk);
        }
        acc = wsum(acc);
        float* psm = smem + 1030;
        if (lane == 0) psm[wid] = u_r * acc;
        __syncthreads();
        if (tid == 0) astore(ws + WS_P + bid, psm[0] + psm[1] + psm[2] + psm[3]);
    }
    gridbar<false>(cnt, bar);

    // ---- final: out = 1e-3 * sum_ij P*W = -1e-4 * sum(partials)
    if (bid == 0) {
        float acc = aload(ws + WS_P + tid);
        acc = wsum(acc);
        float* fsm = smem + 1040;
        if (lane == 0) fsm[wid] = acc;
        __syncthreads();
        if (tid == 0)
            out[0] = -1e-4f * (fsm[0] + fsm[1] + fsm[2] + fsm[3]);
    }
}

extern "C" void kernel_launch(void* const* d_in, const int* in_sizes, int n_in,
                              void* d_out, int out_size, void* d_ws, size_t ws_size,
                              hipStream_t stream) {
    const float* y_s = (const float*)d_in[0];
    const float* y_t = (const float*)d_in[1];
    float* ws = (float*)d_ws;

    // Barrier counter lives in poisoned workspace: zero it every launch
    // (graph-capturable; replayed on every graph execution).
    hipMemsetAsync((char*)d_ws + (size_t)WS_BAR * sizeof(float), 0,
                   sizeof(unsigned), stream);
    sinkhorn_fused<<<dim3(NBLK), dim3(256), 0, stream>>>(y_s, y_t, ws,
                                                         (float*)d_out);
}

// Round 2
// 206.922 us; speedup vs baseline: 1.6315x; 1.6315x over previous
//
#include <hip/hip_runtime.h>

// Sinkhorn, B=8 N=1024 C=64, T=2, eps=0.1, 20 iters, scale=1e-3.
// Only batch 7 contributes (reference returns losses[-1]).
// u = 1/(K v), v = 1/(K^T u), 20 rounds; loss = sum u_i K_ij v_j W_ij,
// W_ij = -0.1*log(K_ij).
//
// ROUND 2: 3 kernels.
//  - softmax_k / buildK_k: unchanged from the 191us baseline (proven bits).
//  - sinkhorn_loop_k: 64-block persistent kernel for the 40 grid-wide
//    dependencies. Per block: 16 K-rows + 16 KT-rows resident in LDS (128KB).
//    Grid barrier = monotonic LLC counter, 64 arrivals (was 256 -> 4x less
//    same-line RMW serialization). u/v exchange: agent-atomic scalar stores
//    (LLC-direct, no fences needed) + vectorized sc0 sc1 dwordx4 loads
//    (forced L1/L2 miss -> reads LLC; waitcnt inside the asm).
//  - Numerics bitwise-identical to the passing baseline (same float4 dot
//    decomposition, same wsum shuffle tree, same loss expression and orders).

static constexpr int N = 1024;
static constexpr int C = 64;

// Workspace layout (floats).
static constexpr int WS_XS  = 0;          // softmax(y_s[7]/2) : 1024*64
static constexpr int WS_YS  = 65536;      // softmax(y_t[7]/2) : 1024*64
static constexpr int WS_K   = 131072;     // K   : 1024*1024
static constexpr int WS_KT  = 1179648;    // K^T : 1024*1024
static constexpr int WS_U   = 2228224;    // u : 1024
static constexpr int WS_V   = 2229248;    // v : 1024
static constexpr int WS_P   = 2230272;    // block partials : 256
static constexpr int WS_BAR = 2230592;    // grid-barrier counter (own line)

typedef float f32x4 __attribute__((ext_vector_type(4)));

__device__ __forceinline__ float wsum(float v) {
    #pragma unroll
    for (int o = 32; o > 0; o >>= 1) v += __shfl_down(v, o, 64);
    return v;
}
__device__ __forceinline__ float wmax(float v) {
    #pragma unroll
    for (int o = 32; o > 0; o >>= 1) v = fmaxf(v, __shfl_down(v, o, 64));
    return v;
}

__device__ __forceinline__ float aload(float* p) {
    return __hip_atomic_load(p, __ATOMIC_RELAXED, __HIP_MEMORY_SCOPE_AGENT);
}
__device__ __forceinline__ void astore(float* p, float v) {
    __hip_atomic_store(p, v, __ATOMIC_RELAXED, __HIP_MEMORY_SCOPE_AGENT);
}

// Coherent wide loads: sc0 sc1 forces L1/L2 miss -> served by the LLC, where
// the agent-scope atomic stores of u/v land. s_waitcnt INSIDE the asm so the
// outputs are valid at asm end (consumers depend on outputs via SSA).
__device__ __forceinline__ void llc_load4(const float* p, f32x4& a0, f32x4& a1,
                                          f32x4& a2, f32x4& a3) {
    asm volatile(
        "global_load_dwordx4 %0, %4, off sc0 sc1\n\t"
        "global_load_dwordx4 %1, %4, off offset:1024 sc0 sc1\n\t"
        "global_load_dwordx4 %2, %4, off offset:2048 sc0 sc1\n\t"
        "global_load_dwordx4 %3, %4, off offset:3072 sc0 sc1\n\t"
        "s_waitcnt vmcnt(0)"
        : "=&v"(a0), "=&v"(a1), "=&v"(a2), "=&v"(a3)
        : "v"(p)
        : "memory");
}
__device__ __forceinline__ void llc_load1(const float* p, f32x4& a0) {
    asm volatile(
        "global_load_dwordx4 %0, %1, off sc0 sc1\n\t"
        "s_waitcnt vmcnt(0)"
        : "=&v"(a0) : "v"(p) : "memory");
}

// Monotonic-counter grid barrier, 64 participants, fence-free (loop data
// moves only through LLC-coherent atomics / sc0sc1 loads).
__device__ __forceinline__ void gridbar64(unsigned* cnt, unsigned& bar) {
    __syncthreads();   // all block stores drained (vmcnt 0) before arrival
    ++bar;
    if (threadIdx.x == 0) {
        __hip_atomic_fetch_add(cnt, 1u, __ATOMIC_RELAXED, __HIP_MEMORY_SCOPE_AGENT);
        while (__hip_atomic_load(cnt, __ATOMIC_RELAXED, __HIP_MEMORY_SCOPE_AGENT)
               < bar * 64u)
            __builtin_amdgcn_s_sleep(1);
    }
    asm volatile("" ::: "memory");
    __syncthreads();
}

// ---- 1: softmax over N axis (dim=1), batch 7. One block per column; 128 blocks.
__global__ void __launch_bounds__(256)
softmax_k(const float* __restrict__ ysrc, const float* __restrict__ ytrc,
          float* __restrict__ ws)
{
    __shared__ float sm[4];
    const int tid = threadIdx.x, bid = blockIdx.x;
    const int wid = tid >> 6, lane = tid & 63;
    const float* src = ((bid < C) ? ysrc : ytrc) + 7 * N * C;
    float* dst = ws + ((bid < C) ? WS_XS : WS_YS);
    const int c = bid & (C - 1);

    float vals[4];
    float m = -1e30f;
    #pragma unroll
    for (int q = 0; q < 4; ++q) {
        vals[q] = src[(q * 256 + tid) * C + c] * 0.5f;   // y / T, T = 2
        m = fmaxf(m, vals[q]);
    }
    m = wmax(m);
    if (lane == 0) sm[wid] = m;
    __syncthreads();
    m = fmaxf(fmaxf(sm[0], sm[1]), fmaxf(sm[2], sm[3]));
    float s = 0.f;
    #pragma unroll
    for (int q = 0; q < 4; ++q) { vals[q] = expf(vals[q] - m); s += vals[q]; }
    s = wsum(s);
    __syncthreads();                 // protect sm reuse
    if (lane == 0) sm[wid] = s;
    __syncthreads();
    s = sm[0] + sm[1] + sm[2] + sm[3];
    const float inv = 1.0f / s;
    #pragma unroll
    for (int q = 0; q < 4; ++q) dst[(q * 256 + tid) * C + c] = vals[q] * inv;
}

// ---- 2: K_ij = exp(-10 * sum_c |x_ic - y_jc|), plus K^T; 32x32 tiles, 4/block.
//        Blocks 0..3 additionally init v = 1; block 0 zeroes the barrier ctr.
__global__ void __launch_bounds__(256)
buildK_k(float* __restrict__ ws)
{
    __shared__ float smem[5184];   // sx 32*64 | sy 32*65 (+1 pad) | kt 32*33
    float* xs  = ws + WS_XS;
    float* ysm = ws + WS_YS;
    float* K   = ws + WS_K;
    float* KT  = ws + WS_KT;
    const int tid = threadIdx.x, bid = blockIdx.x;

    if (bid < 4) ws[WS_V + bid * 256 + tid] = 1.0f;   // v := 1
    if (bid == 0 && tid == 0) *(volatile unsigned*)(ws + WS_BAR) = 0u;

    float* sx = smem;
    float* sy = smem + 2048;
    float* kt = smem + 4128;
    #pragma unroll 1
    for (int t = 0; t < 4; ++t) {
        const int tt = bid * 4 + t;
        const int ti = tt >> 5, tj = tt & 31;
        __syncthreads();
        for (int k = tid; k < 2048; k += 256) sx[k] = xs[ti * 2048 + k];
        for (int k = tid; k < 2048; k += 256)
            sy[(k >> 6) * 65 + (k & 63)] = ysm[tj * 2048 + k];
        __syncthreads();
        float kv[4];
        #pragma unroll
        for (int q = 0; q < 4; ++q) {
            const int idx = q * 256 + tid;
            const int il = idx >> 5, jl = idx & 31;
            float a = 0.f;
            #pragma unroll
            for (int c2 = 0; c2 < 64; ++c2)
                a += fabsf(sx[il * 64 + c2] - sy[jl * 65 + c2]);
            kv[q] = expf(-10.0f * a);                       // exp(-W/eps)
            K[(ti * 32 + il) * N + tj * 32 + jl] = kv[q];   // coalesced over jl
        }
        __syncthreads();
        #pragma unroll
        for (int q = 0; q < 4; ++q) {
            const int idx = q * 256 + tid;
            kt[(idx >> 5) * 33 + (idx & 31)] = kv[q];
        }
        __syncthreads();
        #pragma unroll
        for (int q = 0; q < 4; ++q) {
            const int idx = q * 256 + tid;
            const int jl = idx >> 5, il = idx & 31;
            KT[(tj * 32 + jl) * N + ti * 32 + il] = kt[il * 33 + jl];
        }
    }
}

// ---- 3: persistent loop kernel. 64 blocks x 256 threads; block owns rows
//         bid*16 .. bid*16+15 of both K and KT, resident in LDS.
__global__ void __launch_bounds__(256)
sinkhorn_loop_k(float* __restrict__ ws, float* __restrict__ out)
{
    __shared__ __align__(16) float rows[32 * 1024];  // K rows | KT rows (128KB)
    __shared__ __align__(16) float sv[1024];
    __shared__ float fsm[4];
    const int tid = threadIdx.x, bid = blockIdx.x;
    const int wid = tid >> 6, lane = tid & 63;
    unsigned bar = 0;
    unsigned* cnt = (unsigned*)(ws + WS_BAR);

    // Preload this block's 16 K rows + 16 KT rows (rows are contiguous).
    {
        const f32x4* Ksrc  = (const f32x4*)(ws + WS_K  + bid * 16 * N);
        const f32x4* KTsrc = (const f32x4*)(ws + WS_KT + bid * 16 * N);
        f32x4* dK  = (f32x4*)rows;
        f32x4* dKT = (f32x4*)(rows + 16 * N);
        #pragma unroll 4
        for (int q = 0; q < 16; ++q) dK[tid + 256 * q]  = Ksrc[tid + 256 * q];
        #pragma unroll 4
        for (int q = 0; q < 16; ++q) dKT[tid + 256 * q] = KTsrc[tid + 256 * q];
    }
    __syncthreads();

    float* wsU = ws + WS_U;
    float* wsV = ws + WS_V;
    const float* myU = wsU + lane * 4;     // lane's float4 slices: +0,1,2,3 KB
    const float* myV = wsV + lane * 4;
    const int r0 = bid * 16 + wid * 4;     // wave's 4 rows (== old block bid*4+wid)
    const float* rK  = rows + (wid * 4) * N;
    const float* rKT = rows + 16 * N + (wid * 4) * N;
    float u_s[4];

    #pragma unroll 1
    for (int it = 0; it < 20; ++it) {
        // u = 1/(K v)
        f32x4 b0, b1, b2, b3;
        llc_load4(myV, b0, b1, b2, b3);
        #pragma unroll
        for (int s = 0; s < 4; ++s) {
            const f32x4* Kr = (const f32x4*)(rK + s * N);
            const f32x4 k0 = Kr[lane], k1 = Kr[lane + 64],
                        k2 = Kr[lane + 128], k3 = Kr[lane + 192];
            float acc = 0.f;
            acc += k0.x * b0.x + k0.y * b0.y + k0.z * b0.z + k0.w * b0.w;
            acc += k1.x * b1.x + k1.y * b1.y + k1.z * b1.z + k1.w * b1.w;
            acc += k2.x * b2.x + k2.y * b2.y + k2.z * b2.z + k2.w * b2.w;
            acc += k3.x * b3.x + k3.y * b3.y + k3.z * b3.z + k3.w * b3.w;
            acc = wsum(acc);
            if (lane == 0) { u_s[s] = 1.0f / acc; astore(wsU + r0 + s, u_s[s]); }
        }
        gridbar64(cnt, bar);

        // v = 1/(K^T u)
        llc_load4(myU, b0, b1, b2, b3);
        #pragma unroll
        for (int s = 0; s < 4; ++s) {
            const f32x4* Kr = (const f32x4*)(rKT + s * N);
            const f32x4 k0 = Kr[lane], k1 = Kr[lane + 64],
                        k2 = Kr[lane + 128], k3 = Kr[lane + 192];
            float acc = 0.f;
            acc += k0.x * b0.x + k0.y * b0.y + k0.z * b0.z + k0.w * b0.w;
            acc += k1.x * b1.x + k1.y * b1.y + k1.z * b1.z + k1.w * b1.w;
            acc += k2.x * b2.x + k2.y * b2.y + k2.z * b2.z + k2.w * b2.w;
            acc += k3.x * b3.x + k3.y * b3.y + k3.z * b3.z + k3.w * b3.w;
            acc = wsum(acc);
            if (lane == 0) astore(wsV + r0 + s, 1.0f / acc);
        }
        gridbar64(cnt, bar);
    }

    // Loss. Stage final v into LDS (one float4 per thread), then per wave the
    // 4 rows reproduce the old per-block partial: p = sum_s u_s * acc_s.
    {
        f32x4 vv;
        llc_load1(wsV + tid * 4, vv);
        *(f32x4*)(sv + tid * 4) = vv;
    }
    __syncthreads();
    {
        float p = 0.f;
        #pragma unroll
        for (int s = 0; s < 4; ++s) {
            const float* Kr = rK + s * N;      // LDS copy == K row r0+s bits
            float acc = 0.f;
            for (int j = lane; j < N; j += 64) {
                const float kk = Kr[j];
                acc += kk * sv[j] * logf(kk);
            }
            acc = wsum(acc);
            if (lane == 0) p += u_s[s] * acc;
        }
        if (lane == 0) astore(ws + WS_P + bid * 4 + wid, p);
    }
    gridbar64(cnt, bar);

    // final: out = 1e-3 * sum_ij P*W = -1e-4 * sum(partials)
    if (bid == 0) {
        float acc = aload(ws + WS_P + tid);    // 256 partials, one per thread
        acc = wsum(acc);
        if (lane == 0) fsm[wid] = acc;
        __syncthreads();
        if (tid == 0)
            out[0] = -1e-4f * (fsm[0] + fsm[1] + fsm[2] + fsm[3]);
    }
}

extern "C" void kernel_launch(void* const* d_in, const int* in_sizes, int n_in,
                              void* d_out, int out_size, void* d_ws, size_t ws_size,
                              hipStream_t stream) {
    const float* y_s = (const float*)d_in[0];
    const float* y_t = (const float*)d_in[1];
    float* ws = (float*)d_ws;

    softmax_k<<<dim3(128), dim3(256), 0, stream>>>(y_s, y_t, ws);
    buildK_k<<<dim3(256), dim3(256), 0, stream>>>(ws);
    sinkhorn_loop_k<<<dim3(64), dim3(256), 0, stream>>>(ws, (float*)d_out);
}